// Round 1
// 3715.894 us; speedup vs baseline: 1.0109x; 1.0109x over previous
//
#include <hip/hip_runtime.h>
#include <math.h>

#define DEV __device__ __forceinline__

static constexpr int B_ = 128, T_ = 32, H_ = 512;
static constexpr int S_ = 2048, M_ = 64, OUT_ = 256;
static constexpr int VC_ = 712;   // 256 (vt) + 453 (ctrl), padded to 712
static constexpr float EPSF = 1e-8f;

DEV float sigmoidf_(float x){ return 1.0f/(1.0f+expf(-x)); }
DEV float softplusf_(float x){ return fmaxf(x,0.0f) + log1pf(expf(-fabsf(x))); }

// ---------------- preamble: W_rd [256,256] -> W_rdT ----------------
__global__ __launch_bounds__(256)
void k_transpose_rd(const float* __restrict__ W, float* __restrict__ WT){
  int idx = blockIdx.x*256 + threadIdx.x;  // 65536
  int k = idx>>8, o = idx&255;
  WT[k*256+o] = W[o*256+k];
}

// ---------------- generic fp32 GEMM  C[M,N] = A[M,K] * Bm[N,K]^T ----------------
// 64x64 tile, BK=16, 256 threads, 4x4 micro-tile. Optional split-K via blockIdx.z.
// LDS leading dim padded 64->68 (68%32=4) to kill the 4-way store bank conflict.
__global__ __launch_bounds__(256)
void k_gemm64(const float* __restrict__ A, int lda,
              const float* __restrict__ Bm, int ldb,
              float* __restrict__ C, int ldc,
              int kCount,
              const float* __restrict__ bias0, const float* __restrict__ bias1)
{
  const int BM=64, BN=64, BK=16, LDT=68;
  __shared__ float As[BK*LDT];
  __shared__ float Bs[BK*LDT];
  const int m0 = blockIdx.x*BM, n0 = blockIdx.y*BN;
  const int tid = threadIdx.x;
  const int tx = tid & 15, ty = tid >> 4;
  const int kStart = blockIdx.z * kCount;
  float acc[4][4] = {};
  const int row = tid >> 2, kk = (tid & 3) * 4;
  for(int k0 = kStart; k0 < kStart + kCount; k0 += BK){
    float4 av = *(const float4*)(A  + (size_t)(m0+row)*lda + k0 + kk);
    float4 bv = *(const float4*)(Bm + (size_t)(n0+row)*ldb + k0 + kk);
    As[(kk+0)*LDT+row]=av.x; As[(kk+1)*LDT+row]=av.y; As[(kk+2)*LDT+row]=av.z; As[(kk+3)*LDT+row]=av.w;
    Bs[(kk+0)*LDT+row]=bv.x; Bs[(kk+1)*LDT+row]=bv.y; Bs[(kk+2)*LDT+row]=bv.z; Bs[(kk+3)*LDT+row]=bv.w;
    __syncthreads();
    #pragma unroll
    for(int k=0;k<BK;k++){
      float4 a = *(const float4*)&As[k*LDT + 4*ty];
      float4 b = *(const float4*)&Bs[k*LDT + 4*tx];
      acc[0][0]+=a.x*b.x; acc[0][1]+=a.x*b.y; acc[0][2]+=a.x*b.z; acc[0][3]+=a.x*b.w;
      acc[1][0]+=a.y*b.x; acc[1][1]+=a.y*b.y; acc[1][2]+=a.y*b.z; acc[1][3]+=a.y*b.w;
      acc[2][0]+=a.z*b.x; acc[2][1]+=a.z*b.y; acc[2][2]+=a.z*b.z; acc[2][3]+=a.z*b.w;
      acc[3][0]+=a.w*b.x; acc[3][1]+=a.w*b.y; acc[3][2]+=a.w*b.z; acc[3][3]+=a.w*b.w;
    }
    __syncthreads();
  }
  float* Cz = C + (size_t)blockIdx.z * (size_t)gridDim.x * BM * (size_t)ldc;
  #pragma unroll
  for(int i=0;i<4;i++){
    int m = m0 + 4*ty + i;
    int n = n0 + 4*tx;
    float4 o; o.x=acc[i][0]; o.y=acc[i][1]; o.z=acc[i][2]; o.w=acc[i][3];
    if(bias0){
      o.x += bias0[n]+bias1[n];     o.y += bias0[n+1]+bias1[n+1];
      o.z += bias0[n+2]+bias1[n+2]; o.w += bias0[n+3]+bias1[n+3];
    }
    *(float4*)(Cz + (size_t)m*ldc + n) = o;
  }
}

// ---------------- per-step: LSTM elementwise (sums split-K partials + xg) ----------------
__global__ __launch_bounds__(256)
void k_lstm(const float* __restrict__ xg, const float* __restrict__ gp,
            float* __restrict__ h, float* __restrict__ c, int t)
{
  int idx = blockIdx.x*256 + threadIdx.x;   // 65536 = 128*512
  int b = idx >> 9, j = idx & 511;
  const float* xr = xg + ((size_t)b*T_ + t)*(size_t)(4*H_);
  float gi = xr[j], gf = xr[512+j], gg = xr[1024+j], go = xr[1536+j];
  #pragma unroll
  for(int s4=0;s4<4;s4++){
    const float* pr = gp + ((size_t)s4*B_ + b)*(size_t)(4*H_);
    gi += pr[j]; gf += pr[512+j]; gg += pr[1024+j]; go += pr[1536+j];
  }
  float cc = sigmoidf_(gf)*c[idx] + sigmoidf_(gi)*tanhf(gg);
  float hh = sigmoidf_(go)*tanhf(cc);
  c[idx] = cc; h[idx] = hh;
}

// ---------------- per-step: vt+ctrl GEMM  [128,712] = h[128,512] @ cat(W_out,W_head)^T ----------------
// LDS leading dim padded 32->34 to kill the 16-way store bank conflict.
__global__ __launch_bounds__(256)
void k_vtctrl(const float* __restrict__ h, const float* __restrict__ Wout,
              const float* __restrict__ bout, const float* __restrict__ Whead,
              const float* __restrict__ bhead, float* __restrict__ vc)
{
  const int BM=32, BN=32, BK=16, LDT=34;
  __shared__ float As[BK*LDT], Bs[BK*LDT];
  const int m0 = blockIdx.x*BM, n0 = blockIdx.y*BN;
  const int tid = threadIdx.x, tx = tid&15, ty = tid>>4;
  float acc[2][2] = {};
  for(int k0=0;k0<512;k0+=BK){
    #pragma unroll
    for(int p=0;p<2;p++){
      int idx = tid + p*256;            // 512 elems
      int r = idx>>4, kq = idx&15;
      As[kq*LDT+r] = h[(size_t)(m0+r)*512 + k0+kq];
      int j = n0 + r;
      float v = 0.f;
      if(j < 256)      v = Wout[(size_t)j*512 + k0+kq];
      else if(j < 709) v = Whead[(size_t)(j-256)*512 + k0+kq];
      Bs[kq*LDT+r] = v;
    }
    __syncthreads();
    #pragma unroll
    for(int k=0;k<BK;k++){
      float2 a = *(const float2*)&As[k*LDT + 2*ty];
      float2 b = *(const float2*)&Bs[k*LDT + 2*tx];
      acc[0][0]+=a.x*b.x; acc[0][1]+=a.x*b.y; acc[1][0]+=a.y*b.x; acc[1][1]+=a.y*b.y;
    }
    __syncthreads();
  }
  #pragma unroll
  for(int i=0;i<2;i++){
    int m = m0 + 2*ty + i;
    #pragma unroll
    for(int j2=0;j2<2;j2++){
      int n = n0 + 2*tx + j2;
      if(n < VC_){
        float bv = 0.f;
        if(n < 256) bv = bout[n]; else if(n < 709) bv = bhead[n-256];
        vc[(size_t)m*VC_ + n] = (n < 709) ? acc[i][j2] + bv : 0.f;
      }
    }
  }
}

// ---------------- per-step: all 5 heads' logits over OLD mem (slot-major memC) ----------------
// One thread per slot (x2). Each thread streams its 256 B mem row via float4 —
// cachelines are fully consumed across the 16-load sequence, so this is still
// a linear 64 MB stream, while giving k_heads contiguous per-slot access.
__global__ __launch_bounds__(256)
void k_scores(const float* __restrict__ memC, const float* __restrict__ vc,
              float* __restrict__ scores)
{
  __shared__ float kk[5*64];
  __shared__ float coef[5];
  const int b = blockIdx.x, ch = blockIdx.y, tid = threadIdx.x;  // ch < 4 (512-slot chunks)
  const float* v = vc + (size_t)b*VC_;
  kk[tid] = tanhf(v[256+tid]);                 // kr (256)
  if(tid < 64) kk[256+tid] = tanhf(v[516+tid]);// kw (64)
  __syncthreads();
  if(tid < 5){
    float s = 0.f;
    #pragma unroll
    for(int m=0;m<64;m++){ float x = kk[tid*64+m]; s += x*x; }
    float beta = softplusf_( tid<4 ? v[512+tid] : v[580] );
    coef[tid] = beta / fmaxf(sqrtf(s), EPSF);
  }
  __syncthreads();
  const int s0 = ch*512 + tid;
  const float4* rowA = (const float4*)(memC + ((size_t)b*S_ + s0      )*M_);
  const float4* rowB = (const float4*)(memC + ((size_t)b*S_ + s0 + 256)*M_);
  float nA=0.f,d0A=0.f,d1A=0.f,d2A=0.f,d3A=0.f,dwA=0.f;
  float nB=0.f,d0B=0.f,d1B=0.f,d2B=0.f,d3B=0.f,dwB=0.f;
  #pragma unroll
  for(int r=0;r<16;r++){
    float4 xa = rowA[r];
    float4 xb = rowB[r];
    float av[4] = {xa.x,xa.y,xa.z,xa.w};
    float bv[4] = {xb.x,xb.y,xb.z,xb.w};
    #pragma unroll
    for(int j=0;j<4;j++){
      const int m = r*4+j;
      float a = av[j], q = bv[j];
      float k0=kk[m], k1=kk[64+m], k2=kk[128+m], k3=kk[192+m], k4=kk[256+m];
      nA+=a*a; d0A+=a*k0; d1A+=a*k1; d2A+=a*k2; d3A+=a*k3; dwA+=a*k4;
      nB+=q*q; d0B+=q*k0; d1B+=q*k1; d2B+=q*k2; d3B+=q*k3; dwB+=q*k4;
    }
  }
  float invA = 1.0f / fmaxf(sqrtf(nA), EPSF);
  float invB = 1.0f / fmaxf(sqrtf(nB), EPSF);
  float* sc = scores + (size_t)b*5*(size_t)S_;
  sc[0*S_+s0] = coef[0]*d0A*invA;  sc[0*S_+s0+256] = coef[0]*d0B*invB;
  sc[1*S_+s0] = coef[1]*d1A*invA;  sc[1*S_+s0+256] = coef[1]*d1B*invB;
  sc[2*S_+s0] = coef[2]*d2A*invA;  sc[2*S_+s0+256] = coef[2]*d2B*invB;
  sc[3*S_+s0] = coef[3]*d3A*invA;  sc[3*S_+s0+256] = coef[3]*d3B*invB;
  sc[4*S_+s0] = coef[4]*dwA*invA;  sc[4*S_+s0+256] = coef[4]*dwB*invB;
}

// ---------------- per-step: write head + mem update + read heads + output ----------------
// memC is slot-major [B,S,M]: every per-slot access below is a contiguous 256 B row.
__global__ __launch_bounds__(256)
void k_heads(float* __restrict__ memC,
             const float* __restrict__ scores,
             const float* __restrict__ vc,
             const float* __restrict__ WrdT,
             const float* __restrict__ b_rd,
             float* __restrict__ out, int t)
{
  __shared__ float kr[256];
  __shared__ float er[64], ad[64];
  __shared__ float coefR[4];
  __shared__ float nv[8*64];
  __shared__ int   widx[8];
  __shared__ float wval[8];
  __shared__ float fix[4*8];
  __shared__ float readsv[256];

  const int b = blockIdx.x, tid = threadIdx.x;
  const int lane = tid & 63, wave = tid >> 6;
  const float* v = vc + (size_t)b*VC_;
  const size_t memb = (size_t)b*(size_t)S_*M_;

  // phase 1: parameter transforms
  kr[tid] = tanhf(v[256+tid]);
  if(tid < 64){ er[tid] = sigmoidf_(v[581+tid]); ad[tid] = tanhf(v[645+tid]); }
  __syncthreads();

  // phase 2: write-head softmax stats + top-8 (wave 0); coefR (wave 1)
  if(wave == 1 && lane < 4){
    float s = 0.f;
    #pragma unroll
    for(int m=0;m<64;m++){ float x = kr[lane*64+m]; s += x*x; }
    coefR[lane] = softplusf_(v[512+lane]) / fmaxf(sqrtf(s), EPSF);
  }
  if(wave == 0){
    const float* sw = scores + ((size_t)b*5 + 4)*(size_t)S_;
    float loc[32];
    #pragma unroll
    for(int j=0;j<32;j++) loc[j] = sw[lane + j*64];
    float mx = -INFINITY;
    #pragma unroll
    for(int j=0;j<32;j++) mx = fmaxf(mx, loc[j]);
    #pragma unroll
    for(int off=32; off; off>>=1) mx = fmaxf(mx, __shfl_down(mx, off));
    mx = __shfl(mx, 0);
    float sum = 0.f;
    #pragma unroll
    for(int j=0;j<32;j++) sum += expf(loc[j]-mx);
    #pragma unroll
    for(int off=32; off; off>>=1) sum += __shfl_down(sum, off);
    sum = __shfl(sum, 0);
    float invZ = 1.0f / sum;
    for(int p=0;p<8;p++){
      float bv = -INFINITY; int bi = 0x7fffffff;
      #pragma unroll
      for(int j=0;j<32;j++){            // strict > keeps smallest index in-lane
        float x = loc[j];
        if(x > bv){ bv = x; bi = j*64 + lane; }
      }
      #pragma unroll
      for(int off=32; off; off>>=1){
        float ov = __shfl_down(bv, off); int oi = __shfl_down(bi, off);
        if(ov > bv || (ov == bv && oi < bi)){ bv = ov; bi = oi; }
      }
      bv = __shfl(bv, 0); bi = __shfl(bi, 0);
      if(lane == 0){ widx[p] = bi; wval[p] = expf(bv-mx)*invZ; }
      if((bi & 63) == lane){
        int pos = bi >> 6;
        #pragma unroll
        for(int q=0;q<32;q++) if(q == pos) loc[q] = -INFINITY;
      }
    }
  }
  __syncthreads();

  // phase 3: rank-1 erase/add at the 8 write slots — contiguous 256 B rows now
  #pragma unroll
  for(int p=0;p<2;p++){
    int idx = tid + p*256;              // 512 = 8 slots x 64 dims
    int j = idx >> 6, m = idx & 63;
    int s = widx[j];
    float w = wval[j];
    size_t ptr = memb + (size_t)s*M_ + m;
    float old = memC[ptr];
    float x = old * (1.0f - w*er[m]) + w*ad[m];
    memC[ptr] = x;
    nv[j*64+m] = x;
  }
  __syncthreads();

  // phase 4: recompute read logits at the 8 updated slots
  if(wave < 4){
    #pragma unroll
    for(int q=0;q<2;q++){
      int sl = wave*2 + q;
      float x = nv[sl*64 + lane];
      float n2 = x*x;
      #pragma unroll
      for(int off=32; off; off>>=1) n2 += __shfl_down(n2, off);
      n2 = __shfl(n2, 0);
      float invmn = 1.0f / fmaxf(sqrtf(n2), EPSF);
      #pragma unroll
      for(int r=0;r<4;r++){
        float d = x * kr[r*64+lane];
        #pragma unroll
        for(int off=32; off; off>>=1) d += __shfl_down(d, off);
        if(lane == 0) fix[r*8+sl] = coefR[r] * d * invmn;
      }
    }
  }
  __syncthreads();

  // phase 5: read heads — one wave per head; gathers are contiguous rows
  {
    const int r = wave;
    const float* sr = scores + ((size_t)b*5 + r)*(size_t)S_;
    float loc[32];
    #pragma unroll
    for(int j=0;j<32;j++) loc[j] = sr[lane + j*64];
    #pragma unroll
    for(int p=0;p<8;p++){               // patch updated slots
      int s = widx[p];
      if((s & 63) == lane){
        int pos = s >> 6; float f = fix[r*8+p];
        #pragma unroll
        for(int q=0;q<32;q++) if(q == pos) loc[q] = f;
      }
    }
    float mx = -INFINITY;
    #pragma unroll
    for(int j=0;j<32;j++) mx = fmaxf(mx, loc[j]);
    #pragma unroll
    for(int off=32; off; off>>=1) mx = fmaxf(mx, __shfl_down(mx, off));
    mx = __shfl(mx, 0);
    float sum = 0.f;
    #pragma unroll
    for(int j=0;j<32;j++) sum += expf(loc[j]-mx);
    #pragma unroll
    for(int off=32; off; off>>=1) sum += __shfl_down(sum, off);
    sum = __shfl(sum, 0);
    float invZ = 1.0f / sum;
    float acc = 0.f;                    // reads accumulator; lane == mem dim m
    for(int p=0;p<8;p++){
      float bv = -INFINITY; int bi = 0x7fffffff;
      #pragma unroll
      for(int j=0;j<32;j++){
        float x = loc[j];
        if(x > bv){ bv = x; bi = j*64 + lane; }
      }
      #pragma unroll
      for(int off=32; off; off>>=1){
        float ov = __shfl_down(bv, off); int oi = __shfl_down(bi, off);
        if(ov > bv || (ov == bv && oi < bi)){ bv = ov; bi = oi; }
      }
      bv = __shfl(bv, 0); bi = __shfl(bi, 0);
      if((bi & 63) == lane){
        int pos = bi >> 6;
        #pragma unroll
        for(int q=0;q<32;q++) if(q == pos) loc[q] = -INFINITY;
      }
      float w = expf(bv-mx)*invZ;
      acc += w * memC[memb + (size_t)bi*M_ + lane];   // new mem, contiguous row
    }
    readsv[r*64+lane] = acc;
  }
  __syncthreads();

  // phase 6: out[b,t,:] = vt + reads @ W_rd^T + b_rd  (16 loads in flight, 4 accums)
  {
    const int o = tid;
    float a0=0.f, a1=0.f, a2=0.f, a3=0.f;
    for(int k=0;k<256;k+=16){
      float w[16];
      #pragma unroll
      for(int j=0;j<16;j++) w[j] = WrdT[(size_t)(k+j)*256 + o];
      #pragma unroll
      for(int j=0;j<16;j+=4){
        a0 += readsv[k+j  ]*w[j  ];
        a1 += readsv[k+j+1]*w[j+1];
        a2 += readsv[k+j+2]*w[j+2];
        a3 += readsv[k+j+3]*w[j+3];
      }
    }
    out[((size_t)b*T_ + t)*(size_t)OUT_ + o] = v[o] + b_rd[o] + ((a0+a1)+(a2+a3));
  }
}

// ---------------- host ----------------
extern "C" void kernel_launch(void* const* d_in, const int* in_sizes, int n_in,
                              void* d_out, int out_size, void* d_ws, size_t ws_size,
                              hipStream_t stream)
{
  const float* x     = (const float*)d_in[0];
  const float* h0    = (const float*)d_in[1];
  const float* c0    = (const float*)d_in[2];
  const float* mem0  = (const float*)d_in[3];
  const float* W_ih  = (const float*)d_in[4];
  const float* W_hh  = (const float*)d_in[5];
  const float* b_ih  = (const float*)d_in[6];
  const float* b_hh  = (const float*)d_in[7];
  const float* W_out = (const float*)d_in[8];
  const float* b_out = (const float*)d_in[9];
  const float* W_rd  = (const float*)d_in[10];
  const float* b_rd  = (const float*)d_in[11];
  const float* W_head= (const float*)d_in[12];
  const float* b_head= (const float*)d_in[13];
  // d_in[14] = K (int) — fixed at 8 by the problem setup; hard-coded in k_heads.
  float* out = (float*)d_out;

  float* ws     = (float*)d_ws;
  float* memC   = ws;                    // 128*2048*64  = 16,777,216  (slot-major [B,S,M])
  float* xg     = memC   + 16777216;     // 128*32*2048  =  8,388,608
  float* gparts = xg     + 8388608;      // 4*128*2048   =  1,048,576
  float* scores = gparts + 1048576;      // 128*5*2048   =  1,310,720
  float* vc     = scores + 1310720;      // 128*712      =     91,136
  float* h      = vc     + 91136;        // 128*512      =     65,536
  float* c      = h      + 65536;        // 128*512      =     65,536
  float* WrdT   = c      + 65536;        // 256*256      =     65,536
  const size_t need = (size_t)(27812864) * sizeof(float);
  if(ws_size < need) return;  // ~106 MB workspace required

  hipMemcpyAsync(h, h0, 65536*sizeof(float), hipMemcpyDeviceToDevice, stream);
  hipMemcpyAsync(c, c0, 65536*sizeof(float), hipMemcpyDeviceToDevice, stream);
  hipMemcpyAsync(memC, mem0, (size_t)16777216*sizeof(float), hipMemcpyDeviceToDevice, stream);
  k_transpose_rd<<<256,256,0,stream>>>(W_rd, WrdT);
  // xg[b*T+t, :] = x @ W_ih^T + (b_ih+b_hh)  — hoisted out of the time loop
  k_gemm64<<<dim3(64,32,1),256,0,stream>>>(x,256, W_ih,256, xg,2048, 256, b_ih,b_hh);

  for(int t=0;t<T_;t++){
    // gates partials: h @ W_hh^T, split-K x4 for occupancy (256 blocks)
    k_gemm64<<<dim3(2,32,4),256,0,stream>>>(h,512, W_hh,512, gparts,2048, 128, nullptr,nullptr);
    k_lstm<<<256,256,0,stream>>>(xg, gparts, h, c, t);
    k_vtctrl<<<dim3(4,23),256,0,stream>>>(h, W_out,b_out, W_head,b_head, vc);
    k_scores<<<dim3(128,4),256,0,stream>>>(memC, vc, scores);
    k_heads<<<128,256,0,stream>>>(memC, scores, vc, WrdT, b_rd, out, t);
  }
}

// Round 2
// 2728.333 us; speedup vs baseline: 1.3769x; 1.3620x over previous
//
#include <hip/hip_runtime.h>
#include <math.h>

#define DEV __device__ __forceinline__

static constexpr int B_ = 128, T_ = 32, H_ = 512;
static constexpr int S_ = 2048, M_ = 64, OUT_ = 256;
static constexpr int VC_ = 712;   // 256 (vt) + 453 (ctrl), padded to 712
static constexpr float EPSF = 1e-8f;

DEV float sigmoidf_(float x){ return 1.0f/(1.0f+expf(-x)); }
DEV float softplusf_(float x){ return fmaxf(x,0.0f) + log1pf(expf(-fabsf(x))); }

// ---- packed candidate: (monotonic(value) << 32) | ~idx  => u64 '>' == (value desc, idx asc)
DEV unsigned long long packCand(float v, unsigned idx){
  unsigned u = __float_as_uint(v);
  unsigned m = (u & 0x80000000u) ? ~u : (u | 0x80000000u);
  return ((unsigned long long)m << 32) | (unsigned)(~idx);
}
DEV float unpackVal(unsigned long long e){
  unsigned m = (unsigned)(e >> 32);
  unsigned u = (m & 0x80000000u) ? (m & 0x7FFFFFFFu) : ~m;
  return __uint_as_float(u);
}
DEV unsigned unpackIdx(unsigned long long e){ return ~(unsigned)e; }

DEV void cswp(unsigned long long &a, unsigned long long &b){
  if(a < b){ unsigned long long t=a; a=b; b=t; }   // larger first (descending)
}
// Batcher odd-even mergesort for 8, descending
DEV void sort8(unsigned long long* L){
  cswp(L[0],L[1]); cswp(L[2],L[3]); cswp(L[4],L[5]); cswp(L[6],L[7]);
  cswp(L[0],L[2]); cswp(L[1],L[3]); cswp(L[4],L[6]); cswp(L[5],L[7]);
  cswp(L[1],L[2]); cswp(L[5],L[6]);
  cswp(L[0],L[4]); cswp(L[1],L[5]); cswp(L[2],L[6]); cswp(L[3],L[7]);
  cswp(L[2],L[4]); cswp(L[3],L[5]);
  cswp(L[1],L[2]); cswp(L[3],L[4]); cswp(L[5],L[6]);
}
// butterfly keep-8: each lane holds sorted-8 desc; after steps over xor masks in [1,maxMask],
// every lane holds the sorted top-8 of the union across the lane group.
DEV void butterfly8(unsigned long long* L, int maxMask){
  for(int mask=1; mask<=maxMask; mask<<=1){
    unsigned long long O[8], C[8];
    #pragma unroll
    for(int i=0;i<8;i++) O[i] = __shfl_xor(L[i], mask, 64);
    #pragma unroll
    for(int i=0;i<8;i++){ unsigned long long a=L[i], b=O[7-i]; C[i] = (a>b)?a:b; }
    // bitonic merge desc, strides 4,2,1
    cswp(C[0],C[4]); cswp(C[1],C[5]); cswp(C[2],C[6]); cswp(C[3],C[7]);
    cswp(C[0],C[2]); cswp(C[1],C[3]); cswp(C[4],C[6]); cswp(C[5],C[7]);
    cswp(C[0],C[1]); cswp(C[2],C[3]); cswp(C[4],C[5]); cswp(C[6],C[7]);
    #pragma unroll
    for(int i=0;i<8;i++) L[i]=C[i];
  }
}
// butterfly keep-16 over all 64 lanes (lists sorted-16 desc)
DEV void butterfly16(unsigned long long* L){
  for(int mask=1; mask<64; mask<<=1){
    unsigned long long O[16], C[16];
    #pragma unroll
    for(int i=0;i<16;i++) O[i] = __shfl_xor(L[i], mask, 64);
    #pragma unroll
    for(int i=0;i<16;i++){ unsigned long long a=L[i], b=O[15-i]; C[i] = (a>b)?a:b; }
    // bitonic merge desc, strides 8,4,2,1
    #pragma unroll
    for(int i=0;i<8;i++) cswp(C[i],C[i+8]);
    #pragma unroll
    for(int g=0;g<2;g++){ int o=g*8;
      cswp(C[o+0],C[o+4]); cswp(C[o+1],C[o+5]); cswp(C[o+2],C[o+6]); cswp(C[o+3],C[o+7]); }
    #pragma unroll
    for(int g=0;g<4;g++){ int o=g*4;
      cswp(C[o+0],C[o+2]); cswp(C[o+1],C[o+3]); }
    #pragma unroll
    for(int g=0;g<8;g++){ int o=g*2; cswp(C[o],C[o+1]); }
    #pragma unroll
    for(int i=0;i<16;i++) L[i]=C[i];
  }
}

// ---------------- preamble: W_rd [256,256] -> W_rdT ----------------
__global__ __launch_bounds__(256)
void k_transpose_rd(const float* __restrict__ W, float* __restrict__ WT){
  int idx = blockIdx.x*256 + threadIdx.x;  // 65536
  int k = idx>>8, o = idx&255;
  WT[k*256+o] = W[o*256+k];
}

// ---------------- generic fp32 GEMM  C[M,N] = A[M,K] * Bm[N,K]^T ----------------
__global__ __launch_bounds__(256)
void k_gemm64(const float* __restrict__ A, int lda,
              const float* __restrict__ Bm, int ldb,
              float* __restrict__ C, int ldc,
              int kCount,
              const float* __restrict__ bias0, const float* __restrict__ bias1)
{
  const int BM=64, BN=64, BK=16, LDT=68;
  __shared__ float As[BK*LDT];
  __shared__ float Bs[BK*LDT];
  const int m0 = blockIdx.x*BM, n0 = blockIdx.y*BN;
  const int tid = threadIdx.x;
  const int tx = tid & 15, ty = tid >> 4;
  const int kStart = blockIdx.z * kCount;
  float acc[4][4] = {};
  const int row = tid >> 2, kk = (tid & 3) * 4;
  for(int k0 = kStart; k0 < kStart + kCount; k0 += BK){
    float4 av = *(const float4*)(A  + (size_t)(m0+row)*lda + k0 + kk);
    float4 bv = *(const float4*)(Bm + (size_t)(n0+row)*ldb + k0 + kk);
    As[(kk+0)*LDT+row]=av.x; As[(kk+1)*LDT+row]=av.y; As[(kk+2)*LDT+row]=av.z; As[(kk+3)*LDT+row]=av.w;
    Bs[(kk+0)*LDT+row]=bv.x; Bs[(kk+1)*LDT+row]=bv.y; Bs[(kk+2)*LDT+row]=bv.z; Bs[(kk+3)*LDT+row]=bv.w;
    __syncthreads();
    #pragma unroll
    for(int k=0;k<BK;k++){
      float4 a = *(const float4*)&As[k*LDT + 4*ty];
      float4 b = *(const float4*)&Bs[k*LDT + 4*tx];
      acc[0][0]+=a.x*b.x; acc[0][1]+=a.x*b.y; acc[0][2]+=a.x*b.z; acc[0][3]+=a.x*b.w;
      acc[1][0]+=a.y*b.x; acc[1][1]+=a.y*b.y; acc[1][2]+=a.y*b.z; acc[1][3]+=a.y*b.w;
      acc[2][0]+=a.z*b.x; acc[2][1]+=a.z*b.y; acc[2][2]+=a.z*b.z; acc[2][3]+=a.z*b.w;
      acc[3][0]+=a.w*b.x; acc[3][1]+=a.w*b.y; acc[3][2]+=a.w*b.z; acc[3][3]+=a.w*b.w;
    }
    __syncthreads();
  }
  float* Cz = C + (size_t)blockIdx.z * (size_t)gridDim.x * BM * (size_t)ldc;
  #pragma unroll
  for(int i=0;i<4;i++){
    int m = m0 + 4*ty + i;
    int n = n0 + 4*tx;
    float4 o; o.x=acc[i][0]; o.y=acc[i][1]; o.z=acc[i][2]; o.w=acc[i][3];
    if(bias0){
      o.x += bias0[n]+bias1[n];     o.y += bias0[n+1]+bias1[n+1];
      o.z += bias0[n+2]+bias1[n+2]; o.w += bias0[n+3]+bias1[n+3];
    }
    *(float4*)(Cz + (size_t)m*ldc + n) = o;
  }
}

// ---------------- per-step: LSTM elementwise ----------------
__global__ __launch_bounds__(256)
void k_lstm(const float* __restrict__ xg, const float* __restrict__ gp,
            float* __restrict__ h, float* __restrict__ c, int t)
{
  int idx = blockIdx.x*256 + threadIdx.x;   // 65536 = 128*512
  int b = idx >> 9, j = idx & 511;
  const float* xr = xg + ((size_t)b*T_ + t)*(size_t)(4*H_);
  float gi = xr[j], gf = xr[512+j], gg = xr[1024+j], go = xr[1536+j];
  #pragma unroll
  for(int s4=0;s4<4;s4++){
    const float* pr = gp + ((size_t)s4*B_ + b)*(size_t)(4*H_);
    gi += pr[j]; gf += pr[512+j]; gg += pr[1024+j]; go += pr[1536+j];
  }
  float cc = sigmoidf_(gf)*c[idx] + sigmoidf_(gi)*tanhf(gg);
  float hh = sigmoidf_(go)*tanhf(cc);
  c[idx] = cc; h[idx] = hh;
}

// ---------------- per-step: vt+ctrl GEMM ----------------
__global__ __launch_bounds__(256)
void k_vtctrl(const float* __restrict__ h, const float* __restrict__ Wout,
              const float* __restrict__ bout, const float* __restrict__ Whead,
              const float* __restrict__ bhead, float* __restrict__ vc)
{
  const int BM=32, BN=32, BK=16, LDT=34;
  __shared__ float As[BK*LDT], Bs[BK*LDT];
  const int m0 = blockIdx.x*BM, n0 = blockIdx.y*BN;
  const int tid = threadIdx.x, tx = tid&15, ty = tid>>4;
  float acc[2][2] = {};
  for(int k0=0;k0<512;k0+=BK){
    #pragma unroll
    for(int p=0;p<2;p++){
      int idx = tid + p*256;
      int r = idx>>4, kq = idx&15;
      As[kq*LDT+r] = h[(size_t)(m0+r)*512 + k0+kq];
      int j = n0 + r;
      float v = 0.f;
      if(j < 256)      v = Wout[(size_t)j*512 + k0+kq];
      else if(j < 709) v = Whead[(size_t)(j-256)*512 + k0+kq];
      Bs[kq*LDT+r] = v;
    }
    __syncthreads();
    #pragma unroll
    for(int k=0;k<BK;k++){
      float2 a = *(const float2*)&As[k*LDT + 2*ty];
      float2 b = *(const float2*)&Bs[k*LDT + 2*tx];
      acc[0][0]+=a.x*b.x; acc[0][1]+=a.x*b.y; acc[1][0]+=a.y*b.x; acc[1][1]+=a.y*b.y;
    }
    __syncthreads();
  }
  #pragma unroll
  for(int i=0;i<2;i++){
    int m = m0 + 2*ty + i;
    #pragma unroll
    for(int j2=0;j2<2;j2++){
      int n = n0 + 2*tx + j2;
      if(n < VC_){
        float bv = 0.f;
        if(n < 256) bv = bout[n]; else if(n < 709) bv = bhead[n-256];
        vc[(size_t)m*VC_ + n] = (n < 709) ? acc[i][j2] + bv : 0.f;
      }
    }
  }
}

// ---------------- per-step: logits + per-chunk stats + per-chunk topk candidates ----------------
// grid (128, 4), 512 threads (8 waves). One slot per thread; then per-wave tasks:
// waves 0-3: sorted top-16 candidates for read heads 0-3; wave 4: sorted top-8 for write head;
// waves 5-7: (max, sum-exp) stats for heads {0,1},{2,3},{4}.
__global__ __launch_bounds__(512,4)
void k_scores(const float* __restrict__ memC, const float* __restrict__ vc,
              float* __restrict__ scores,
              unsigned long long* __restrict__ candW,
              unsigned long long* __restrict__ candR,
              float* __restrict__ statsB)
{
  __shared__ float kk[5*64];
  __shared__ float coef[5];
  __shared__ float tile[5*512];
  const int b = blockIdx.x, ch = blockIdx.y, tid = threadIdx.x;
  const int lane = tid & 63, wid = tid >> 6;
  const float* v = vc + (size_t)b*VC_;
  if(tid < 256) kk[tid] = tanhf(v[256+tid]);           // kr (4x64)
  else if(tid < 320) kk[tid] = tanhf(v[516 + tid-256]);// kw (64)
  __syncthreads();
  if(tid < 5){
    float s = 0.f;
    #pragma unroll
    for(int m=0;m<64;m++){ float x = kk[tid*64+m]; s += x*x; }
    float beta = softplusf_( tid<4 ? v[512+tid] : v[580] );
    coef[tid] = beta / fmaxf(sqrtf(s), EPSF);
  }
  __syncthreads();

  // logits for this thread's slot
  {
    const int s = ch*512 + tid;
    const float4* row = (const float4*)(memC + ((size_t)b*S_ + s)*M_);
    float nrm=0.f, d0=0.f, d1=0.f, d2=0.f, d3=0.f, dw=0.f;
    #pragma unroll
    for(int r4=0;r4<16;r4++){
      float4 xa = row[r4];
      float av[4] = {xa.x,xa.y,xa.z,xa.w};
      #pragma unroll
      for(int j=0;j<4;j++){
        const int m = r4*4+j;
        float a = av[j];
        nrm += a*a;
        d0 += a*kk[m];     d1 += a*kk[64+m]; d2 += a*kk[128+m];
        d3 += a*kk[192+m]; dw += a*kk[256+m];
      }
    }
    float inv = 1.0f / fmaxf(sqrtf(nrm), EPSF);
    float l0 = coef[0]*d0*inv, l1 = coef[1]*d1*inv, l2 = coef[2]*d2*inv;
    float l3 = coef[3]*d3*inv, l4 = coef[4]*dw*inv;
    float* sc = scores + (size_t)b*5*(size_t)S_;
    sc[0*S_+s]=l0; sc[1*S_+s]=l1; sc[2*S_+s]=l2; sc[3*S_+s]=l3; sc[4*S_+s]=l4;
    tile[0*512+tid]=l0; tile[1*512+tid]=l1; tile[2*512+tid]=l2;
    tile[3*512+tid]=l3; tile[4*512+tid]=l4;
  }
  __syncthreads();

  if(wid < 4){
    // read head wid: sorted top-16 of this chunk
    unsigned long long L[16];
    #pragma unroll
    for(int j=0;j<8;j++){
      int i = lane + j*64;
      L[j] = packCand(tile[wid*512 + i], (unsigned)(ch*512 + i));
    }
    sort8(L);
    #pragma unroll
    for(int j=8;j<16;j++) L[j] = 0ULL;
    butterfly16(L);
    if(lane == 0){
      unsigned long long* dst = candR + (((size_t)b*4 + ch)*4 + wid)*16;
      #pragma unroll
      for(int j=0;j<16;j++) dst[j] = L[j];
    }
  } else if(wid == 4){
    // write head: sorted top-8 of this chunk
    unsigned long long L[8];
    #pragma unroll
    for(int j=0;j<8;j++){
      int i = lane + j*64;
      L[j] = packCand(tile[4*512 + i], (unsigned)(ch*512 + i));
    }
    sort8(L);
    butterfly8(L, 32);
    if(lane == 0){
      unsigned long long* dst = candW + ((size_t)b*4 + ch)*8;
      #pragma unroll
      for(int j=0;j<8;j++) dst[j] = L[j];
    }
  } else {
    // stats waves: wid 5 -> heads 0,1; wid 6 -> heads 2,3; wid 7 -> head 4
    int h0 = (wid==5) ? 0 : (wid==6) ? 2 : 4;
    int nh = (wid==7) ? 1 : 2;
    for(int q=0;q<nh;q++){
      int h = h0 + q;
      float x[8];
      #pragma unroll
      for(int j=0;j<8;j++) x[j] = tile[h*512 + lane + j*64];
      float mx = x[0];
      #pragma unroll
      for(int j=1;j<8;j++) mx = fmaxf(mx, x[j]);
      #pragma unroll
      for(int mask=1; mask<64; mask<<=1) mx = fmaxf(mx, __shfl_xor(mx, mask, 64));
      float sm = 0.f;
      #pragma unroll
      for(int j=0;j<8;j++) sm += expf(x[j]-mx);
      #pragma unroll
      for(int mask=1; mask<64; mask<<=1) sm += __shfl_xor(sm, mask, 64);
      if(lane == 0){
        float* st = statsB + (((size_t)b*4 + ch)*5 + h)*2;
        st[0] = mx; st[1] = sm;
      }
    }
  }
}

// ---------------- per-step: write head + mem update + read heads + output ----------------
__global__ __launch_bounds__(256)
void k_heads(float* __restrict__ memC,
             const float* __restrict__ scores,
             const float* __restrict__ vc,
             const unsigned long long* __restrict__ candW,
             const unsigned long long* __restrict__ candR,
             const float* __restrict__ statsB,
             const float* __restrict__ WrdT,
             const float* __restrict__ b_rd,
             float* __restrict__ out, int t)
{
  __shared__ float kr[256];
  __shared__ float er[64], ad[64];
  __shared__ float coefR[4];
  __shared__ float nv[512];
  __shared__ int   widx[8];
  __shared__ float wval[8];
  __shared__ float readsv[256];

  const int b = blockIdx.x, tid = threadIdx.x;
  const int lane = tid & 63, wave = tid >> 6;
  const float* v = vc + (size_t)b*VC_;
  const size_t memb = (size_t)b*(size_t)S_*M_;

  // phase 1: parameter transforms (+ early loads for phase 6)
  float vt_o = v[tid];
  float brd_o = b_rd[tid];
  kr[tid] = tanhf(v[256+tid]);
  if(tid < 64){ er[tid] = sigmoidf_(v[581+tid]); ad[tid] = tanhf(v[645+tid]); }
  __syncthreads();

  // phase 2: write-head selection (wave 0, lanes 0-31 hold 4 chunks x sorted-8), coefR (wave 1)
  if(wave == 0){
    float smx[4], ssm[4];
    #pragma unroll
    for(int c=0;c<4;c++){
      const float* st = statsB + (((size_t)b*4 + c)*5 + 4)*2;
      smx[c] = st[0]; ssm[c] = st[1];
    }
    float mxw = fmaxf(fmaxf(smx[0],smx[1]), fmaxf(smx[2],smx[3]));
    float Zw = ssm[0]*expf(smx[0]-mxw) + ssm[1]*expf(smx[1]-mxw)
             + ssm[2]*expf(smx[2]-mxw) + ssm[3]*expf(smx[3]-mxw);
    unsigned long long L[8];
    L[0] = (lane < 32) ? candW[((size_t)b*4 + (lane>>3))*8 + (lane&7)] : 0ULL;
    #pragma unroll
    for(int j=1;j<8;j++) L[j] = 0ULL;
    butterfly8(L, 16);                 // lanes 0-31 contain the data; 5 steps suffice
    if(lane == 0){
      float invZ = 1.0f / Zw;
      #pragma unroll
      for(int p=0;p<8;p++){
        widx[p] = (int)unpackIdx(L[p]);
        wval[p] = expf(unpackVal(L[p]) - mxw) * invZ;
      }
    }
  } else if(wave == 1 && lane < 4){
    float s = 0.f;
    #pragma unroll
    for(int m=0;m<64;m++){ float x = kr[lane*64+m]; s += x*x; }
    coefR[lane] = softplusf_(v[512+lane]) / fmaxf(sqrtf(s), EPSF);
  }
  __syncthreads();

  // phase 3: rank-1 erase/add at the 8 write slots (contiguous 256 B rows)
  #pragma unroll
  for(int p=0;p<2;p++){
    int idx = tid + p*256;              // 512 = 8 slots x 64 dims
    int j = idx >> 6, m = idx & 63;
    int s = widx[j];
    float w = wval[j];
    size_t ptr = memb + (size_t)s*M_ + m;
    float old = memC[ptr];
    float x = old * (1.0f - w*er[m]) + w*ad[m];
    memC[ptr] = x;
    nv[j*64+m] = x;
  }
  __syncthreads();

  // phases 4+5 fused, one wave per read head r
  {
    const int r = wave;
    const int sW = lane & 7, g = lane >> 3;
    // fix logit for written slot sW: dot(nv_s, kr_r) * coefR / ||nv_s||
    const float4* nv4 = (const float4*)nv;
    const float4* kr4 = (const float4*)kr;
    float4 na = nv4[sW*16 + g*2], nb = nv4[sW*16 + g*2 + 1];
    float4 ka = kr4[r*16  + g*2], kb = kr4[r*16  + g*2 + 1];
    float dot = na.x*ka.x + na.y*ka.y + na.z*ka.z + na.w*ka.w
              + nb.x*kb.x + nb.y*kb.y + nb.z*kb.z + nb.w*kb.w;
    float n2  = na.x*na.x + na.y*na.y + na.z*na.z + na.w*na.w
              + nb.x*nb.x + nb.y*nb.y + nb.z*nb.z + nb.w*nb.w;
    #pragma unroll
    for(int mask=8; mask<64; mask<<=1){
      dot += __shfl_xor(dot, mask, 64);
      n2  += __shfl_xor(n2,  mask, 64);
    }
    float fixv = coefR[r] * dot / fmaxf(sqrtf(n2), EPSF);
    int myw = widx[sW];
    float oldv = scores[((size_t)b*5 + r)*(size_t)S_ + myw];   // pre-patch logit of written slot

    // pre-patch chunk stats for this head
    float scx[4], scs[4];
    #pragma unroll
    for(int c=0;c<4;c++){
      const float* st = statsB + (((size_t)b*4 + c)*5 + r)*2;
      scx[c] = st[0]; scs[c] = st[1];
    }
    float mxp = fmaxf(fmaxf(scx[0],scx[1]), fmaxf(scx[2],scx[3]));

    // candidates: 64 chunk entries (invalidate written) + 8 written entries with new logits
    unsigned long long L[8];
    {
      int c = lane >> 4, rank = lane & 15;
      unsigned long long eA = candR[(((size_t)b*4 + c)*4 + r)*16 + rank];
      unsigned idxA = unpackIdx(eA);
      bool kill = false;
      #pragma unroll
      for(int p=0;p<8;p++) kill = kill || (idxA == (unsigned)widx[p]);
      if(kill) eA = 0ULL;
      unsigned long long eB = (lane < 8) ? packCand(fixv, (unsigned)myw) : 0ULL;
      L[0] = (eA > eB) ? eA : eB;
      L[1] = (eA > eB) ? eB : eA;
      #pragma unroll
      for(int j=2;j<8;j++) L[j] = 0ULL;
    }
    butterfly8(L, 32);                 // all lanes -> global post-patch sorted top-8

    // exact denominator: Z' = Z_pre(mxS) - sum exp(old) + sum exp(new)
    float mxS = fmaxf(mxp, unpackVal(L[0]));
    float Zp = scs[0]*expf(scx[0]-mxS) + scs[1]*expf(scx[1]-mxS)
             + scs[2]*expf(scx[2]-mxS) + scs[3]*expf(scx[3]-mxS);
    float adj = (lane < 8) ? (expf(fixv - mxS) - expf(oldv - mxS)) : 0.f;
    #pragma unroll
    for(int mask=1; mask<64; mask<<=1) adj += __shfl_xor(adj, mask, 64);
    float invZ = 1.0f / (Zp + adj);

    float acc = 0.f;                   // lane == mem dim m
    #pragma unroll
    for(int p=0;p<8;p++){
      float w = expf(unpackVal(L[p]) - mxS) * invZ;
      int si = (int)unpackIdx(L[p]);
      acc += w * memC[memb + (size_t)si*M_ + lane];   // new mem, contiguous row
    }
    readsv[r*64 + lane] = acc;
  }

  // phase 6: out[b,t,:] = vt + reads @ W_rd^T + b_rd  (32-wide batches, batch-0 prefetched)
  float wb[32];
  #pragma unroll
  for(int j=0;j<32;j++) wb[j] = WrdT[(size_t)j*256 + tid];
  __syncthreads();
  {
    float a0=0.f, a1=0.f, a2=0.f, a3=0.f;
    #pragma unroll
    for(int kb=0;kb<256;kb+=32){
      float wn[32];
      if(kb+32 < 256){
        #pragma unroll
        for(int j=0;j<32;j++) wn[j] = WrdT[(size_t)(kb+32+j)*256 + tid];
      }
      #pragma unroll
      for(int j=0;j<32;j+=4){
        a0 += readsv[kb+j  ]*wb[j  ];
        a1 += readsv[kb+j+1]*wb[j+1];
        a2 += readsv[kb+j+2]*wb[j+2];
        a3 += readsv[kb+j+3]*wb[j+3];
      }
      if(kb+32 < 256){
        #pragma unroll
        for(int j=0;j<32;j++) wb[j] = wn[j];
      }
    }
    out[((size_t)b*T_ + t)*(size_t)OUT_ + tid] = vt_o + brd_o + ((a0+a1)+(a2+a3));
  }
}

// ---------------- host ----------------
extern "C" void kernel_launch(void* const* d_in, const int* in_sizes, int n_in,
                              void* d_out, int out_size, void* d_ws, size_t ws_size,
                              hipStream_t stream)
{
  const float* x     = (const float*)d_in[0];
  const float* h0    = (const float*)d_in[1];
  const float* c0    = (const float*)d_in[2];
  const float* mem0  = (const float*)d_in[3];
  const float* W_ih  = (const float*)d_in[4];
  const float* W_hh  = (const float*)d_in[5];
  const float* b_ih  = (const float*)d_in[6];
  const float* b_hh  = (const float*)d_in[7];
  const float* W_out = (const float*)d_in[8];
  const float* b_out = (const float*)d_in[9];
  const float* W_rd  = (const float*)d_in[10];
  const float* b_rd  = (const float*)d_in[11];
  const float* W_head= (const float*)d_in[12];
  const float* b_head= (const float*)d_in[13];
  // d_in[14] = K (int) — fixed at 8 by the problem setup; hard-coded in k_heads.
  float* out = (float*)d_out;

  float* ws     = (float*)d_ws;
  float* memC   = ws;                    // 128*2048*64  = 16,777,216  (slot-major [B,S,M])
  float* xg     = memC   + 16777216;     // 128*32*2048  =  8,388,608
  float* gparts = xg     + 8388608;      // 4*128*2048   =  1,048,576
  float* scores = gparts + 1048576;      // 128*5*2048   =  1,310,720
  float* vc     = scores + 1310720;      // 128*712      =     91,136
  float* h      = vc     + 91136;        // 128*512      =     65,536
  float* c      = h      + 65536;        // 128*512      =     65,536
  float* WrdT   = c      + 65536;        // 256*256      =     65,536
  // candidate/stat buffers overlay gparts (lifetimes disjoint within a step):
  // gparts live: k_gemm64 -> k_lstm; cand/stats live: k_scores -> k_heads.
  unsigned long long* candW  = (unsigned long long*)gparts;     // 128*4*8  u64 (8192 floats)
  unsigned long long* candR  = candW + 4096;                    // 128*4*4*16 u64 (65536 floats)
  float*              statsB = (float*)(candR + 32768);         // 128*4*5*2 = 5120 floats
  const size_t need = (size_t)(27812864) * sizeof(float);
  if(ws_size < need) return;  // ~106 MB workspace required

  hipMemcpyAsync(h, h0, 65536*sizeof(float), hipMemcpyDeviceToDevice, stream);
  hipMemcpyAsync(c, c0, 65536*sizeof(float), hipMemcpyDeviceToDevice, stream);
  hipMemcpyAsync(memC, mem0, (size_t)16777216*sizeof(float), hipMemcpyDeviceToDevice, stream);
  k_transpose_rd<<<256,256,0,stream>>>(W_rd, WrdT);
  // xg[b*T+t, :] = x @ W_ih^T + (b_ih+b_hh)  — hoisted out of the time loop
  k_gemm64<<<dim3(64,32,1),256,0,stream>>>(x,256, W_ih,256, xg,2048, 256, b_ih,b_hh);

  for(int t=0;t<T_;t++){
    k_gemm64<<<dim3(2,32,4),256,0,stream>>>(h,512, W_hh,512, gparts,2048, 128, nullptr,nullptr);
    k_lstm<<<256,256,0,stream>>>(xg, gparts, h, c, t);
    k_vtctrl<<<dim3(4,23),256,0,stream>>>(h, W_out,b_out, W_head,b_head, vc);
    k_scores<<<dim3(128,4),512,0,stream>>>(memC, vc, scores, candW, candR, statsB);
    k_heads<<<128,256,0,stream>>>(memC, scores, vc, candW, candR, statsB, WrdT, b_rd, out, t);
  }
}